// Round 6
// baseline (91.696 us; speedup 1.0000x reference)
//
#include <hip/hip_runtime.h>

// N_RNA=20000, N_PROT=5000, D=128, C=4, E=500000
#define DIM 128
#define NCLS 4
#define UNIT 16   // edges per unit = one 16-col MFMA group
#define ITER 8    // units per wave

typedef _Float16 f16x8 __attribute__((ext_vector_type(8)));
typedef float    f32x4 __attribute__((ext_vector_type(4)));

// ---------- merged fp32 -> fp16 conversion (both tables, one launch) ----------
__global__ __launch_bounds__(256) void cvt_both_kernel(
    const float* __restrict__ s1, _Float16* __restrict__ d1, int n1,
    const float* __restrict__ s2, _Float16* __restrict__ d2, int n2)
{
    const int total = n1 + n2;
    int i = (blockIdx.x * blockDim.x + threadIdx.x) * 8;
    const int stride = gridDim.x * blockDim.x * 8;
    for (; i < total; i += stride) {
        const float* s; _Float16* d; int j;
        if (i < n1) { s = s1; d = d1; j = i; }
        else        { s = s2; d = d2; j = i - n1; }
        const float4 a = *(const float4*)(s + j);
        const float4 b = *(const float4*)(s + j + 4);
        f16x8 o;
        o[0] = (_Float16)a.x; o[1] = (_Float16)a.y;
        o[2] = (_Float16)a.z; o[3] = (_Float16)a.w;
        o[4] = (_Float16)b.x; o[5] = (_Float16)b.y;
        o[6] = (_Float16)b.z; o[7] = (_Float16)b.w;
        *(f16x8*)(d + j) = o;
    }
}

// ---------- coalesced-gather q-premultiply LDS-transpose MFMA decoder ----------
// R5 (verified, 91.3us): coalesced row loads (each dwordx4 = 4 full 256B rows,
// 8 fully-used 128B transactions) + per-wave LDS transpose halved the decoder's
// TA-transaction cost: 34.4 -> ~19.6us. Remaining top term: DS pipe, 16 b128
// ops/unit (~192cy).
// This round: compute q = r .* p IN REGISTERS at stage time — the staging lane
// already holds r-row and p-row bytes of the SAME edge and d-slice — and write
// only q to LDS: 4 ds_write_b128 + 4 ds_read_b128 per unit (DS halved), LDS
// slice 8KB -> 4KB. Same pk_mul count (moved, not added), same XOR swizzle,
// same fragment k-slices, same MFMA order -> bitwise-identical output.
//   Stage (lane h=lane>>4, sl=lane&15), i=0..3: edge row e=4h+i,
//     q = rna[ri[e]][sl*8..+8] * prot[pi[e]][sl*8..+8]  (f16 packed mul)
//     LDS: slice + e*256 + ((sl ^ e) << 4)
//   Frag read (lane l16, kg), f: slot t = (4f+kg) ^ l16 of row l16
//     -> d-slice (t^l16)=4f+kg -> k = f*32+kg*8..+7  (B operand of 16x16x32).
//   D layout col=lane&15, row=(lane>>4)*4+reg: lanes 0..15 hold class float4.
__global__ __launch_bounds__(256, 4) void decoder_lds_kernel(
    const _Float16* __restrict__ rna,   // [N_RNA, D] f16
    const _Float16* __restrict__ prot,  // [N_PROT, D] f16
    const int*   __restrict__ ridx,
    const int*   __restrict__ pidx,
    const float* __restrict__ wrel,
    const float* __restrict__ wcls,
    float*       __restrict__ out,
    int nEdges)                          // requires nEdges % 32 == 0
{
    __shared__ _Float16 wf_lds[NCLS][DIM];
    __shared__ __align__(16) char stage[4][UNIT * 256];   // 4 waves x 4KB q-slices
    {
        const int t = threadIdx.x;
        if (t < DIM) {
            const float w0 = wrel[0 * DIM + t];
            const float w1 = wrel[1 * DIM + t];
            const float w2 = wrel[2 * DIM + t];
            const float w3 = wrel[3 * DIM + t];
#pragma unroll
            for (int c = 0; c < NCLS; ++c) {
                wf_lds[c][t] = (_Float16)(w0 * wcls[0 * 4 + c] + w1 * wcls[1 * 4 + c] +
                                          w2 * wcls[2 * 4 + c] + w3 * wcls[3 * 4 + c]);
            }
        }
    }
    __syncthreads();

    const int lane = threadIdx.x & 63;
    const int l16  = lane & 15;   // edge-in-group (B cols) / class row (A)
    const int kg   = lane >> 4;   // k-subgroup 0..3 (8 f16 each)

    f16x8 awf[4];
    const f16x8 fz = {};
#pragma unroll
    for (int f = 0; f < 4; ++f)
        awf[f] = (l16 < NCLS) ? *(const f16x8*)(&wf_lds[l16][f * 32 + kg * 8]) : fz;

    char* slice = stage[threadIdx.x >> 6];

    const int wid = blockIdx.x * 4 + (threadIdx.x >> 6);
    const int nU  = nEdges >> 4;          // 16-edge units
    const int u0  = wid * ITER;

    const int h4   = (lane >> 4) << 2;    // row-group base 4*(lane/16)
    const int sl16 = (lane & 15) << 4;    // byte-in-row for coalesced stage load

    const char* rna8  = (const char*)rna;
    const char* prot8 = (const char*)prot;

    bool vu[ITER];
    int  eu[ITER];
#pragma unroll
    for (int u = 0; u < ITER; ++u) {
        const int un = u0 + u;
        vu[u] = un < nU;
        eu[u] = vu[u] ? (un << 4) : 0;    // invalid units read row-0 area, skip store
    }

    int4  riv[2], piv[2];                 // idx slots (compile-time indexed)
    f16x8 stg[2][8];                      // depth-2 staging regs (r rows, p rows)

#define LOADIDX(u_, s_) do {                                     \
        riv[s_] = *(const int4*)(ridx + eu[u_] + h4);            \
        piv[s_] = *(const int4*)(pidx + eu[u_] + h4); } while (0)

#define GLOB1(s_, op_, i_, idx_)                                                 \
        stg[s_][(op_) * 4 + (i_)] =                                              \
            *(const f16x8*)(((op_) ? prot8 : rna8) + ((size_t)(idx_) << 8) + sl16)

#define GLOB(s_) do {                                            \
        GLOB1(s_, 0, 0, riv[s_].x); GLOB1(s_, 0, 1, riv[s_].y);  \
        GLOB1(s_, 0, 2, riv[s_].z); GLOB1(s_, 0, 3, riv[s_].w);  \
        GLOB1(s_, 1, 0, piv[s_].x); GLOB1(s_, 1, 1, piv[s_].y);  \
        GLOB1(s_, 1, 2, piv[s_].z); GLOB1(s_, 1, 3, piv[s_].w); } while (0)

// q = r*p in regs (waits vmcnt for this slot's loads), then one b128 write.
#define QDSW1(s_, i_) do {                                                       \
        const f16x8 q_ = stg[s_][i_] * stg[s_][4 + (i_)];                        \
        *(f16x8*)(slice + (h4 + (i_)) * 256 +                                    \
                  (((lane & 15) ^ (h4 + (i_))) << 4)) = q_; } while (0)

#define QDSW(s_) do { QDSW1(s_, 0); QDSW1(s_, 1); QDSW1(s_, 2); QDSW1(s_, 3); } while (0)

    // prologue: idx(0) -> glob(0) in flight; idx(1) in flight
    LOADIDX(0, 0);
    GLOB(0);
    LOADIDX(1, 1);

#pragma unroll
    for (int u = 0; u < ITER; ++u) {
        const int s  = u & 1;
        const int ns = s ^ 1;
        if (u + 1 < ITER) GLOB(ns);           // issue next unit's row loads
        if (u + 2 < ITER) LOADIDX(u + 2, s);  // idx two units ahead

        QDSW(s);   // vmcnt-waits glob(u) only; glob(u+1) stays in flight

        f32x4 acc = {};
#pragma unroll
        for (int f = 0; f < 4; ++f) {
            const int t = ((f << 2) | kg) ^ l16;
            const f16x8 q = *(const f16x8*)(slice + l16 * 256 + (t << 4));
            acc = __builtin_amdgcn_mfma_f32_16x16x32_f16(awf[f], q, acc, 0, 0, 0);
        }

        if (lane < 16 && vu[u]) {
            f32x4 o;
#pragma unroll
            for (int j = 0; j < 4; ++j) o[j] = fmaxf(acc[j], 0.0f);
            *(f32x4*)(out + (size_t)(eu[u] + l16) * NCLS) = o;
        }
    }
#undef LOADIDX
#undef GLOB1
#undef GLOB
#undef QDSW1
#undef QDSW
}

// ---------- fp32 fallback (handles any shape / tiny workspace) ----------
__device__ __forceinline__ float reduce4_f32(float b0, float b1, float b2, float b3, int lane)
{
    const bool lo1 = (lane & 1) == 0;
    float k0 = lo1 ? b0 : b2, s0 = lo1 ? b2 : b0;
    float k1 = lo1 ? b1 : b3, s1 = lo1 ? b3 : b1;
    float v0 = k0 + __shfl_xor(s0, 1, 32);
    float v1 = k1 + __shfl_xor(s1, 1, 32);
    const bool lo2 = (lane & 2) == 0;
    float k = lo2 ? v0 : v1, s = lo2 ? v1 : v0;
    float v = k + __shfl_xor(s, 2, 32);
    v += __shfl_xor(v, 4, 32);
    v += __shfl_xor(v, 8, 32);
    v += __shfl_xor(v, 16, 32);
    return v;
}

__global__ __launch_bounds__(256) void decoder_f32_kernel(
    const float* __restrict__ rna, const float* __restrict__ prot,
    const int* __restrict__ ridx, const int* __restrict__ pidx,
    const float* __restrict__ wrel, const float* __restrict__ wcls,
    float* __restrict__ out, int nEdges)
{
    const int lane32 = threadIdx.x & 31;
    const int hw     = (blockIdx.x * blockDim.x + threadIdx.x) >> 5;
    const int nhw    = (gridDim.x * blockDim.x) >> 5;
    const float4 w0 = *(const float4*)(wrel + 0 * DIM + lane32 * 4);
    const float4 w1 = *(const float4*)(wrel + 1 * DIM + lane32 * 4);
    const float4 w2 = *(const float4*)(wrel + 2 * DIM + lane32 * 4);
    const float4 w3 = *(const float4*)(wrel + 3 * DIM + lane32 * 4);
    float wc[16];
#pragma unroll
    for (int i = 0; i < 16; ++i) wc[i] = wcls[i];
    float4 wf[4];
#pragma unroll
    for (int j = 0; j < 4; ++j) {
        wf[j].x = wc[j] * w0.x + wc[4 + j] * w1.x + wc[8 + j] * w2.x + wc[12 + j] * w3.x;
        wf[j].y = wc[j] * w0.y + wc[4 + j] * w1.y + wc[8 + j] * w2.y + wc[12 + j] * w3.y;
        wf[j].z = wc[j] * w0.z + wc[4 + j] * w1.z + wc[8 + j] * w2.z + wc[12 + j] * w3.z;
        wf[j].w = wc[j] * w0.w + wc[4 + j] * w1.w + wc[8 + j] * w2.w + wc[12 + j] * w3.w;
    }
    const int cls   = ((lane32 & 1) << 1) | ((lane32 >> 1) & 1);
    const int lelem = lane32 * 4;
    for (int e = hw; e < nEdges; e += nhw) {
        const float4 r = *(const float4*)(rna  + (size_t)ridx[e] * DIM + lelem);
        const float4 p = *(const float4*)(prot + (size_t)pidx[e] * DIM + lelem);
        float qx = r.x * p.x, qy = r.y * p.y, qz = r.z * p.z, qw = r.w * p.w;
        float b0 = qx * wf[0].x + qy * wf[0].y + qz * wf[0].z + qw * wf[0].w;
        float b1 = qx * wf[1].x + qy * wf[1].y + qz * wf[1].z + qw * wf[1].w;
        float b2 = qx * wf[2].x + qy * wf[2].y + qz * wf[2].z + qw * wf[2].w;
        float b3 = qx * wf[3].x + qy * wf[3].y + qz * wf[3].z + qw * wf[3].w;
        const float v = reduce4_f32(b0, b1, b2, b3, lane32);
        if (lane32 < 4) out[(size_t)e * NCLS + cls] = fmaxf(v, 0.0f);
    }
}

extern "C" void kernel_launch(void* const* d_in, const int* in_sizes, int n_in,
                              void* d_out, int out_size, void* d_ws, size_t ws_size,
                              hipStream_t stream) {
    const float* rna  = (const float*)d_in[0];
    const float* prot = (const float*)d_in[1];
    const int*   ridx = (const int*)d_in[2];
    const int*   pidx = (const int*)d_in[3];
    const float* wrel = (const float*)d_in[4];
    const float* wcls = (const float*)d_in[5];
    float*       out  = (float*)d_out;

    const int nRnaElems  = in_sizes[0];   // 20000*128
    const int nProtElems = in_sizes[1];   // 5000*128
    const int nEdges     = in_sizes[2];   // 500000

    const size_t rnaBytes  = (size_t)nRnaElems * 2;
    const size_t needBytes = rnaBytes + (size_t)nProtElems * 2;

    if (ws_size >= needBytes && (nEdges % 32) == 0 && nEdges >= 32 &&
        (nRnaElems % 8) == 0 && (nProtElems % 8) == 0) {
        _Float16* rnaH  = (_Float16*)d_ws;
        _Float16* protH = (_Float16*)((char*)d_ws + rnaBytes);

        const int totalElems = nRnaElems + nProtElems;
        const int cvtBlocks  = (totalElems / 8 + 255) / 256;
        hipLaunchKernelGGL(cvt_both_kernel, dim3(cvtBlocks), dim3(256), 0, stream,
                           rna, rnaH, nRnaElems, prot, protH, nProtElems);

        // 16-edge units, 8 units/wave, 4 waves/block.
        // E=500000 -> 31250 units -> 3907 waves -> 977 blocks; at
        // __launch_bounds__(256,4) + 17KB LDS/block = 4 blocks/CU -> 1024
        // resident: the whole grid is co-resident (no tail round).
        const int nU     = nEdges >> 4;
        const int waves  = (nU + ITER - 1) / ITER;
        const int blocks = (waves + 3) / 4;
        hipLaunchKernelGGL(decoder_lds_kernel, dim3(blocks), dim3(256), 0, stream,
                           rnaH, protH, ridx, pidx, wrel, wcls, out, nEdges);
    } else {
        hipLaunchKernelGGL(decoder_f32_kernel, dim3(8192), dim3(256), 0, stream,
                           rna, prot, ridx, pidx, wrel, wcls, out, nEdges);
    }
}